// Round 7
// baseline (581.581 us; speedup 1.0000x reference)
//
#include <hip/hip_runtime.h>
#include <cstdint>
#include <cstddef>

#define T_ 3
#define B_ 2
#define Y_ 192
#define X_ 192
#define YX_ 36864          // Y_*X_
#define N_ 221184          // T_*B_*Y_*X_
#define NS_ 73728          // B_*Y_*X_

typedef __attribute__((ext_vector_type(8))) short short8;
typedef __attribute__((ext_vector_type(4))) float f32x4;
typedef __attribute__((ext_vector_type(2))) float f32x2;
typedef unsigned short u16;
typedef unsigned int u32;

__device__ __forceinline__ u16 f2bf(float f){
  u32 x = __builtin_bit_cast(u32, f);
  x += 0x7fffu + ((x >> 16) & 1u);          // RNE
  return (u16)(x >> 16);
}
__device__ __forceinline__ float bflo(u32 u){ return __builtin_bit_cast(float, u << 16); }
__device__ __forceinline__ float bfhi(u32 u){ return __builtin_bit_cast(float, u & 0xffff0000u); }
__device__ __forceinline__ f32x2 bfp(u32 u){
  f32x2 r; r.x = bflo(u); r.y = bfhi(u); return r;
}
__device__ __forceinline__ int clampi(int v, int lo, int hi){ return v < lo ? lo : (v > hi ? hi : v); }
__device__ __forceinline__ f32x2 shfl2(f32x2 v, int m){
  f32x2 r; r.x = __shfl_xor(v.x, m); r.y = __shfl_xor(v.y, m); return r;
}

#if __has_builtin(__builtin_amdgcn_fdot2_f32_bf16)
typedef __attribute__((ext_vector_type(2))) __bf16 bf16x2;
__device__ __forceinline__ float dot2bf(u32 a, u32 b, float c){
  return __builtin_amdgcn_fdot2_f32_bf16(__builtin_bit_cast(bf16x2, a),
                                         __builtin_bit_cast(bf16x2, b), c, false);
}
#else
__device__ __forceinline__ float dot2bf(u32 a, u32 b, float c){
  return fmaf(bfhi(a), bfhi(b), fmaf(bflo(a), bflo(b), c));
}
#endif

#if __has_builtin(__builtin_amdgcn_exp2f)
__device__ __forceinline__ float fexp2(float x){ return __builtin_amdgcn_exp2f(x); }
#else
__device__ __forceinline__ float fexp2(float x){ return exp2f(x); }
#endif

// Q prescale: 1/sqrt(F) * log2(e), so score exp() becomes exp2() with no extra mul
#define QSCALE 0.36067376022224085f

// ---------------- kernel 0: weights -> bf16 n-major; spatial_emb -> bf16 ----------------
__global__ __launch_bounds__(256) void wt_kernel(
    const float* __restrict__ Wq, const float* __restrict__ Wk,
    const float* __restrict__ Wv, const float* __restrict__ Wo,
    const float* __restrict__ spatial_emb, u16* __restrict__ WT, u16* __restrict__ se_bf){
  int idx = blockIdx.x * 256 + threadIdx.x;
  if (idx < 65536){
    int g = idx >> 14;
    int r = (idx >> 7) & 127;                   // k
    int c = idx & 127;                          // n
    const float* W = (g == 0) ? Wq : (g == 1) ? Wk : (g == 2) ? Wv : Wo;
    WT[g * 16384 + c * 128 + r] = f2bf(W[r * 128 + c]);
  } else if (idx < 65536 + 3200){
    se_bf[idx - 65536] = f2bf(spatial_emb[idx - 65536]);
  }
}

// ---------------- kernel 1: fused QKV projection + embeddings ----------------
// grid (N_/128, 3); g 0=Q ((v+te+se)*QSCALE), 1=K (+te), 2=V
__global__ __launch_bounds__(256) void qkv_kernel(
    const float* __restrict__ frames, const u16* __restrict__ WT,
    u16* __restrict__ Qb, u16* __restrict__ Kb, u16* __restrict__ Vb,
    const float* __restrict__ temp_emb, const float* __restrict__ spatial_emb){
  __shared__ float tile[128 * 128];
  const int tid = threadIdx.x;
  const int w = tid >> 6, l = tid & 63;
  const int l16 = l & 15, lg = l >> 4;
  const int g = blockIdx.y;
  const int m0 = blockIdx.x * 128;
  const u16* wt = WT + g * 16384;

  f32x4 acc[2][8];
  #pragma unroll
  for (int mr = 0; mr < 2; ++mr)
    #pragma unroll
    for (int nf = 0; nf < 8; ++nf)
      acc[mr][nf] = (f32x4){0.f, 0.f, 0.f, 0.f};

  #pragma unroll
  for (int ks = 0; ks < 4; ++ks){
    short8 af[2];
    #pragma unroll
    for (int mr = 0; mr < 2; ++mr){
      const float* ap = frames + (size_t)(m0 + w * 32 + mr * 16 + l16) * 128 + ks * 32 + lg * 8;
      const f32x4 a0 = *(const f32x4*)ap;
      const f32x4 a1 = *(const f32x4*)(ap + 4);
      short8 t;
      t[0] = (short)f2bf(a0[0]); t[1] = (short)f2bf(a0[1]);
      t[2] = (short)f2bf(a0[2]); t[3] = (short)f2bf(a0[3]);
      t[4] = (short)f2bf(a1[0]); t[5] = (short)f2bf(a1[1]);
      t[6] = (short)f2bf(a1[2]); t[7] = (short)f2bf(a1[3]);
      af[mr] = t;
    }
    #pragma unroll
    for (int nf = 0; nf < 8; ++nf){
      const short8 bf = *(const short8*)(wt + (nf * 16 + l16) * 128 + ks * 32 + lg * 8);
      acc[0][nf] = __builtin_amdgcn_mfma_f32_16x16x32_bf16(af[0], bf, acc[0][nf], 0, 0, 0);
      acc[1][nf] = __builtin_amdgcn_mfma_f32_16x16x32_bf16(af[1], bf, acc[1][nf], 0, 0, 0);
    }
  }

  #pragma unroll
  for (int mr = 0; mr < 2; ++mr)
    #pragma unroll
    for (int nf = 0; nf < 8; ++nf)
      #pragma unroll
      for (int i = 0; i < 4; ++i)
        tile[(w * 32 + mr * 16 + lg * 4 + i) * 128 + nf * 16 + l16] = acc[mr][nf][i];
  __syncthreads();

  u16* outp = (g == 0) ? Qb : (g == 1) ? Kb : Vb;
  #pragma unroll
  for (int it = 0; it < 16; ++it){
    const int idx = it * 256 + tid;
    const int r = idx >> 5;
    const int c4 = (idx & 31) * 4;
    f32x4 v = *(const f32x4*)&tile[r * 128 + c4];
    const int p = m0 + r;
    const int t = p / (B_ * YX_);
    if (g <= 1){                          // temporal emb for Q and K
      const float* te = temp_emb + t * 128 + c4;
      v[0] += te[0]; v[1] += te[1]; v[2] += te[2]; v[3] += te[3];
    }
    if (g == 0){                          // query spatial emb + QSCALE prescale
      const int yx = p % YX_;
      const int y = yx / X_, x = yx % X_;
      const int yrel = y - clampi(y, 2, Y_ - 3) + 2;
      const int xrel = x - clampi(x, 2, X_ - 3) + 2;
      const float* se = spatial_emb + (yrel * 5 + xrel) * 128 + c4;
      v[0] = (v[0] + se[0]) * QSCALE; v[1] = (v[1] + se[1]) * QSCALE;
      v[2] = (v[2] + se[2]) * QSCALE; v[3] = (v[3] + se[3]) * QSCALE;
    }
    uint2 pk;
    pk.x = (u32)f2bf(v[0]) | ((u32)f2bf(v[1]) << 16);
    pk.y = (u32)f2bf(v[2]) | ((u32)f2bf(v[3]) << 16);
    *(uint2*)(outp + (size_t)p * 128 + c4) = pk;
  }
}

// ---------------- kernel 2: scalar attention, 8 key-slots x 8 heads, prefetched ----------------
// 1 wave per site; lane (slot=l>>3, h=l&7) owns all 16 ch of head h for keys slot, slot+8, ...
// Q/K bf16-packed, v_dot2_f32_bf16 scores, exp2 softmax, 1-iter K/V+qse register prefetch.
__global__ __launch_bounds__(256, 4) void attn_kernel(
    const u16* __restrict__ Kb, const u16* __restrict__ Vb,
    u16* __restrict__ Qb, const u16* __restrict__ se_bf){
  __shared__ float qse[4][600];            // [wave][q*200 + s*8 + h]
  const int tid = threadIdx.x;
  const int w = tid >> 6, l = tid & 63;
  const int slot = l >> 3, h = l & 7;

  // XCD-aware swizzle: 18432 blocks = 8 XCDs x 2304 contiguous
  const int bid = blockIdx.x;
  const int sw = (bid & 7) * 2304 + (bid >> 3);
  const int site = sw * 4 + w;
  const int b = site / YX_;
  const int yx = site % YX_;
  const int y = yx / X_, x = yx % X_;
  const int yc = clampi(y, 2, 189), xc = clampi(x, 2, 189);

  // Q packed (prescaled by QSCALE, + temp & query-spatial emb)
  u32 qp[3][8];
  #pragma unroll
  for (int q = 0; q < 3; ++q){
    const u16* qptr = Qb + ((size_t)((q * B_ + b) * Y_ + y) * X_ + x) * 128 + h * 16;
    const uint4 a = *(const uint4*)qptr;
    const uint4 c = *(const uint4*)(qptr + 8);
    qp[q][0] = a.x; qp[q][1] = a.y; qp[q][2] = a.z; qp[q][3] = a.w;
    qp[q][4] = c.x; qp[q][5] = c.y; qp[q][6] = c.z; qp[q][7] = c.w;
  }

  // qse[q][so][h] = Qs . spatial_emb[so] (per head), so striped over slots
  #pragma unroll
  for (int sj = 0; sj < 4; ++sj){
    const int so = sj * 8 + slot;
    if (so < 25){
      const u16* sp = se_bf + so * 128 + h * 16;
      const uint4 e0 = *(const uint4*)sp;
      const uint4 e1 = *(const uint4*)(sp + 8);
      u32 ep[8] = {e0.x, e0.y, e0.z, e0.w, e1.x, e1.y, e1.z, e1.w};
      #pragma unroll
      for (int q = 0; q < 3; ++q){
        float d = 0.f;
        #pragma unroll
        for (int i = 0; i < 8; ++i) d = dot2bf(qp[q][i], ep[i], d);
        qse[w][q * 200 + so * 8 + h] = d;
      }
    }
  }
  __syncthreads();

  float ll[3] = {0.f, 0.f, 0.f};
  f32x2 acc[3][8];
  #pragma unroll
  for (int q = 0; q < 3; ++q)
    #pragma unroll
    for (int i = 0; i < 8; ++i) acc[q][i] = (f32x2){0.f, 0.f};

  const int h16 = h * 16;

  // ---- prefetch j = 0 ----
  uint4 k0n, k1n, v0n, v1n;
  float qn0, qn1, qn2;
  {
    const int kkc = slot;                     // j=0 always valid
    const int t = (kkc * 41) >> 10;
    const int s = kkc - t * 25;
    const int dy = (s * 205) >> 10, dx = s - dy * 5;
    const u32 roff = (u32)((((t * B_ + b) * Y_ + (yc + dy - 2)) * X_ + (xc + dx - 2)) * 128 + h16);
    k0n = *(const uint4*)(Kb + roff);
    k1n = *(const uint4*)(Kb + roff + 8);
    v0n = *(const uint4*)(Vb + roff);
    v1n = *(const uint4*)(Vb + roff + 8);
    qn0 = qse[w][0 * 200 + s * 8 + h];
    qn1 = qse[w][1 * 200 + s * 8 + h];
    qn2 = qse[w][2 * 200 + s * 8 + h];
  }

  #pragma unroll
  for (int j = 0; j < 10; ++j){
    const uint4 k0 = k0n, k1 = k1n, v0 = v0n, v1 = v1n;
    const float q0 = qn0, q1 = qn1, q2 = qn2;

    if (j < 9){                               // prefetch j+1
      const int kk = (j + 1) * 8 + slot;
      const bool vnext = (j + 1 < 9) || (slot < 3);
      const int kkc = vnext ? kk : 74;
      const int t = (kkc * 41) >> 10;
      const int s = kkc - t * 25;
      const int dy = (s * 205) >> 10, dx = s - dy * 5;
      const u32 roff = (u32)((((t * B_ + b) * Y_ + (yc + dy - 2)) * X_ + (xc + dx - 2)) * 128 + h16);
      k0n = *(const uint4*)(Kb + roff);
      k1n = *(const uint4*)(Kb + roff + 8);
      v0n = *(const uint4*)(Vb + roff);
      v1n = *(const uint4*)(Vb + roff + 8);
      qn0 = qse[w][0 * 200 + s * 8 + h];
      qn1 = qse[w][1 * 200 + s * 8 + h];
      qn2 = qse[w][2 * 200 + s * 8 + h];
    }

    const bool valid = (j < 9) || (slot < 3);
    const u32 kp[8] = {k0.x, k0.y, k0.z, k0.w, k1.x, k1.y, k1.z, k1.w};
    f32x2 vf[8];
    vf[0] = bfp(v0.x); vf[1] = bfp(v0.y); vf[2] = bfp(v0.z); vf[3] = bfp(v0.w);
    vf[4] = bfp(v1.x); vf[5] = bfp(v1.y); vf[6] = bfp(v1.z); vf[7] = bfp(v1.w);

    float dq[3] = {q0, q1, q2};
    #pragma unroll
    for (int q = 0; q < 3; ++q){
      float d = dq[q];
      #pragma unroll
      for (int i = 0; i < 8; ++i) d = dot2bf(qp[q][i], kp[i], d);
      const float p = valid ? fexp2(d) : 0.f;
      ll[q] += p;
      const f32x2 pp = {p, p};
      #pragma unroll
      for (int i = 0; i < 8; ++i) acc[q][i] += pp * vf[i];
    }
  }

  // merge across the 8 key-slot groups (lanes xor 8/16/32 share the same head)
  #pragma unroll
  for (int q = 0; q < 3; ++q){
    ll[q] += __shfl_xor(ll[q], 8);
    ll[q] += __shfl_xor(ll[q], 16);
    ll[q] += __shfl_xor(ll[q], 32);
    #pragma unroll
    for (int i = 0; i < 8; ++i){
      acc[q][i] += shfl2(acc[q][i], 8);
      acc[q][i] += shfl2(acc[q][i], 16);
      acc[q][i] += shfl2(acc[q][i], 32);
    }
  }

  // slot-group q (<3) stores query-frame q's output over its Q row (8 lanes x 32B = 256B)
  #pragma unroll
  for (int q = 0; q < 3; ++q){
    if (slot == q){
      const float inv = 1.0f / ll[q];
      uint4 o0, o1;
      {
        const f32x2 t0 = acc[q][0] * inv, t1 = acc[q][1] * inv;
        const f32x2 t2 = acc[q][2] * inv, t3 = acc[q][3] * inv;
        o0.x = (u32)f2bf(t0.x) | ((u32)f2bf(t0.y) << 16);
        o0.y = (u32)f2bf(t1.x) | ((u32)f2bf(t1.y) << 16);
        o0.z = (u32)f2bf(t2.x) | ((u32)f2bf(t2.y) << 16);
        o0.w = (u32)f2bf(t3.x) | ((u32)f2bf(t3.y) << 16);
      }
      {
        const f32x2 t0 = acc[q][4] * inv, t1 = acc[q][5] * inv;
        const f32x2 t2 = acc[q][6] * inv, t3 = acc[q][7] * inv;
        o1.x = (u32)f2bf(t0.x) | ((u32)f2bf(t0.y) << 16);
        o1.y = (u32)f2bf(t1.x) | ((u32)f2bf(t1.y) << 16);
        o1.z = (u32)f2bf(t2.x) | ((u32)f2bf(t2.y) << 16);
        o1.w = (u32)f2bf(t3.x) | ((u32)f2bf(t3.y) << 16);
      }
      u16* dst = Qb + ((size_t)((q * B_ + b) * Y_ + y) * X_ + x) * 128 + h16;
      *(uint4*)dst = o0;
      *(uint4*)(dst + 8) = o1;
    }
  }
}

// ---------------- kernel 3: output projection (attnout x Wout) ----------------
__global__ __launch_bounds__(256) void out_kernel(
    const u16* __restrict__ Ab, const u16* __restrict__ WT3, float* __restrict__ out){
  const int tid = threadIdx.x;
  const int w = tid >> 6, l = tid & 63;
  const int l16 = l & 15, lg = l >> 4;
  const int m0 = blockIdx.x * 128;

  f32x4 acc[2][8];
  #pragma unroll
  for (int mr = 0; mr < 2; ++mr)
    #pragma unroll
    for (int nf = 0; nf < 8; ++nf)
      acc[mr][nf] = (f32x4){0.f, 0.f, 0.f, 0.f};

  #pragma unroll
  for (int ks = 0; ks < 4; ++ks){
    short8 af[2];
    #pragma unroll
    for (int mr = 0; mr < 2; ++mr)
      af[mr] = *(const short8*)(Ab + (size_t)(m0 + w * 32 + mr * 16 + l16) * 128 + ks * 32 + lg * 8);
    #pragma unroll
    for (int nf = 0; nf < 8; ++nf){
      const short8 bf = *(const short8*)(WT3 + (nf * 16 + l16) * 128 + ks * 32 + lg * 8);
      acc[0][nf] = __builtin_amdgcn_mfma_f32_16x16x32_bf16(af[0], bf, acc[0][nf], 0, 0, 0);
      acc[1][nf] = __builtin_amdgcn_mfma_f32_16x16x32_bf16(af[1], bf, acc[1][nf], 0, 0, 0);
    }
  }

  #pragma unroll
  for (int mr = 0; mr < 2; ++mr)
    #pragma unroll
    for (int nf = 0; nf < 8; ++nf)
      #pragma unroll
      for (int i = 0; i < 4; ++i)
        out[(size_t)(m0 + w * 32 + mr * 16 + lg * 4 + i) * 128 + nf * 16 + l16] = acc[mr][nf][i];
}

extern "C" void kernel_launch(void* const* d_in, const int* in_sizes, int n_in,
                              void* d_out, int out_size, void* d_ws, size_t ws_size,
                              hipStream_t stream){
  const float* frames      = (const float*)d_in[0];
  const float* Wq          = (const float*)d_in[1];
  const float* Wk          = (const float*)d_in[2];
  const float* Wv          = (const float*)d_in[3];
  const float* Wo          = (const float*)d_in[4];
  const float* temp_emb    = (const float*)d_in[5];
  const float* spatial_emb = (const float*)d_in[6];

  u16* WT    = (u16*)d_ws;                      // [4][128][128] bf16 (n-major)
  u16* se_bf = WT + 4 * 16384;                  // [25][128] bf16
  u16* Qb    = WT + 68736;                      // [N_][128] bf16 (Q, then attnout)
  u16* Kb    = (u16*)d_out;                     // [N_][128] bf16 — reuse output buffer
  u16* Vb    = Kb + (size_t)N_ * 128;           // [N_][128] bf16 — exactly fills d_out
  float* out = (float*)d_out;

  wt_kernel<<<269, 256, 0, stream>>>(Wq, Wk, Wv, Wo, spatial_emb, WT, se_bf);
  qkv_kernel<<<dim3(N_ / 128, 3), 256, 0, stream>>>(frames, WT, Qb, Kb, Vb, temp_emb, spatial_emb);
  attn_kernel<<<NS_ / 4, 256, 0, stream>>>(Kb, Vb, Qb, se_bf);
  out_kernel<<<N_ / 128, 256, 0, stream>>>(Qb, WT + 3 * 16384, out);
}

// Round 8
// 404.552 us; speedup vs baseline: 1.4376x; 1.4376x over previous
//
#include <hip/hip_runtime.h>
#include <cstdint>
#include <cstddef>

#define T_ 3
#define B_ 2
#define Y_ 192
#define X_ 192
#define YX_ 36864          // Y_*X_
#define N_ 221184          // T_*B_*Y_*X_
#define NS_ 73728          // B_*Y_*X_

typedef __attribute__((ext_vector_type(8))) short short8;
typedef __attribute__((ext_vector_type(4))) float f32x4;
typedef __attribute__((ext_vector_type(2))) float f32x2;
typedef unsigned short u16;
typedef unsigned int u32;

__device__ __forceinline__ u16 f2bf(float f){
  u32 x = __builtin_bit_cast(u32, f);
  x += 0x7fffu + ((x >> 16) & 1u);          // RNE
  return (u16)(x >> 16);
}
__device__ __forceinline__ float bflo(u32 u){ return __builtin_bit_cast(float, u << 16); }
__device__ __forceinline__ float bfhi(u32 u){ return __builtin_bit_cast(float, u & 0xffff0000u); }
__device__ __forceinline__ f32x2 bfp(u32 u){
  f32x2 r; r.x = bflo(u); r.y = bfhi(u); return r;
}
__device__ __forceinline__ int clampi(int v, int lo, int hi){ return v < lo ? lo : (v > hi ? hi : v); }
__device__ __forceinline__ f32x2 shfl2(f32x2 v, int m){
  f32x2 r; r.x = __shfl_xor(v.x, m); r.y = __shfl_xor(v.y, m); return r;
}

#if __has_builtin(__builtin_amdgcn_fdot2_f32_bf16)
typedef __attribute__((ext_vector_type(2))) __bf16 bf16x2;
__device__ __forceinline__ float dot2bf(u32 a, u32 b, float c){
  return __builtin_amdgcn_fdot2_f32_bf16(__builtin_bit_cast(bf16x2, a),
                                         __builtin_bit_cast(bf16x2, b), c, false);
}
#else
__device__ __forceinline__ float dot2bf(u32 a, u32 b, float c){
  return fmaf(bfhi(a), bfhi(b), fmaf(bflo(a), bflo(b), c));
}
#endif

#if __has_builtin(__builtin_amdgcn_exp2f)
__device__ __forceinline__ float fexp2(float x){ return __builtin_amdgcn_exp2f(x); }
#else
__device__ __forceinline__ float fexp2(float x){ return exp2f(x); }
#endif

// Q prescale: 1/sqrt(F) * log2(e), so score exp() becomes exp2() with no extra mul
#define QSCALE 0.36067376022224085f

// ---------------- kernel 0: weights -> bf16 n-major; spatial_emb -> bf16 ----------------
__global__ __launch_bounds__(256) void wt_kernel(
    const float* __restrict__ Wq, const float* __restrict__ Wk,
    const float* __restrict__ Wv, const float* __restrict__ Wo,
    const float* __restrict__ spatial_emb, u16* __restrict__ WT, u16* __restrict__ se_bf){
  int idx = blockIdx.x * 256 + threadIdx.x;
  if (idx < 65536){
    int g = idx >> 14;
    int r = (idx >> 7) & 127;                   // k
    int c = idx & 127;                          // n
    const float* W = (g == 0) ? Wq : (g == 1) ? Wk : (g == 2) ? Wv : Wo;
    WT[g * 16384 + c * 128 + r] = f2bf(W[r * 128 + c]);
  } else if (idx < 65536 + 3200){
    se_bf[idx - 65536] = f2bf(spatial_emb[idx - 65536]);
  }
}

// ---------------- kernel 1: fused QKV projection + embeddings ----------------
// grid (N_/128, 3); g 0=Q ((v+te+se)*QSCALE), 1=K (+te), 2=V
__global__ __launch_bounds__(256) void qkv_kernel(
    const float* __restrict__ frames, const u16* __restrict__ WT,
    u16* __restrict__ Qb, u16* __restrict__ Kb, u16* __restrict__ Vb,
    const float* __restrict__ temp_emb, const float* __restrict__ spatial_emb){
  __shared__ float tile[128 * 128];
  const int tid = threadIdx.x;
  const int w = tid >> 6, l = tid & 63;
  const int l16 = l & 15, lg = l >> 4;
  const int g = blockIdx.y;
  const int m0 = blockIdx.x * 128;
  const u16* wt = WT + g * 16384;

  f32x4 acc[2][8];
  #pragma unroll
  for (int mr = 0; mr < 2; ++mr)
    #pragma unroll
    for (int nf = 0; nf < 8; ++nf)
      acc[mr][nf] = (f32x4){0.f, 0.f, 0.f, 0.f};

  #pragma unroll
  for (int ks = 0; ks < 4; ++ks){
    short8 af[2];
    #pragma unroll
    for (int mr = 0; mr < 2; ++mr){
      const float* ap = frames + (size_t)(m0 + w * 32 + mr * 16 + l16) * 128 + ks * 32 + lg * 8;
      const f32x4 a0 = *(const f32x4*)ap;
      const f32x4 a1 = *(const f32x4*)(ap + 4);
      short8 t;
      t[0] = (short)f2bf(a0[0]); t[1] = (short)f2bf(a0[1]);
      t[2] = (short)f2bf(a0[2]); t[3] = (short)f2bf(a0[3]);
      t[4] = (short)f2bf(a1[0]); t[5] = (short)f2bf(a1[1]);
      t[6] = (short)f2bf(a1[2]); t[7] = (short)f2bf(a1[3]);
      af[mr] = t;
    }
    #pragma unroll
    for (int nf = 0; nf < 8; ++nf){
      const short8 bf = *(const short8*)(wt + (nf * 16 + l16) * 128 + ks * 32 + lg * 8);
      acc[0][nf] = __builtin_amdgcn_mfma_f32_16x16x32_bf16(af[0], bf, acc[0][nf], 0, 0, 0);
      acc[1][nf] = __builtin_amdgcn_mfma_f32_16x16x32_bf16(af[1], bf, acc[1][nf], 0, 0, 0);
    }
  }

  #pragma unroll
  for (int mr = 0; mr < 2; ++mr)
    #pragma unroll
    for (int nf = 0; nf < 8; ++nf)
      #pragma unroll
      for (int i = 0; i < 4; ++i)
        tile[(w * 32 + mr * 16 + lg * 4 + i) * 128 + nf * 16 + l16] = acc[mr][nf][i];
  __syncthreads();

  u16* outp = (g == 0) ? Qb : (g == 1) ? Kb : Vb;
  #pragma unroll
  for (int it = 0; it < 16; ++it){
    const int idx = it * 256 + tid;
    const int r = idx >> 5;
    const int c4 = (idx & 31) * 4;
    f32x4 v = *(const f32x4*)&tile[r * 128 + c4];
    const int p = m0 + r;
    const int t = p / (B_ * YX_);
    if (g <= 1){                          // temporal emb for Q and K
      const float* te = temp_emb + t * 128 + c4;
      v[0] += te[0]; v[1] += te[1]; v[2] += te[2]; v[3] += te[3];
    }
    if (g == 0){                          // query spatial emb + QSCALE prescale
      const int yx = p % YX_;
      const int y = yx / X_, x = yx % X_;
      const int yrel = y - clampi(y, 2, Y_ - 3) + 2;
      const int xrel = x - clampi(x, 2, X_ - 3) + 2;
      const float* se = spatial_emb + (yrel * 5 + xrel) * 128 + c4;
      v[0] = (v[0] + se[0]) * QSCALE; v[1] = (v[1] + se[1]) * QSCALE;
      v[2] = (v[2] + se[2]) * QSCALE; v[3] = (v[3] + se[3]) * QSCALE;
    }
    uint2 pk;
    pk.x = (u32)f2bf(v[0]) | ((u32)f2bf(v[1]) << 16);
    pk.y = (u32)f2bf(v[2]) | ((u32)f2bf(v[3]) << 16);
    *(uint2*)(outp + (size_t)p * 128 + c4) = pk;
  }
}

// ---------------- kernel 2: scalar attention, 2 sites x 4 key-slots x 8 heads per wave ----------
// lane (s2=l>>5, slot=(l>>3)&3, h=l&7): site s2, head h (16ch), keys slot, slot+4, ...
// Merge over slots = 2 shuffle levels (xor 8/16). Offset table in LDS kills per-key decode.
__global__ __launch_bounds__(256, 4) void attn_kernel(
    const u16* __restrict__ Kb, const u16* __restrict__ Vb,
    u16* __restrict__ Qb, const u16* __restrict__ se_bf){
  __shared__ float qse[4][2][600];          // [wave][site2][q*200 + s*8 + h]
  __shared__ u32 tbl[80];                   // byte offset (x256) | s*8 in low byte
  const int tid = threadIdx.x;
  const int w = tid >> 6, l = tid & 63;
  const int s2 = l >> 5, slot = (l >> 3) & 3, h = l & 7;

  if (tid < 80){                            // offset table (padded: 75..79 -> key 74)
    const int kk = tid > 74 ? 74 : tid;
    const int t = kk / 25, s = kk - t * 25;
    const int dy = s / 5, dx = s - dy * 5;
    tbl[tid] = (u32)((((t * (B_ * Y_) + dy) * X_ + dx) * 256) | (s * 8));
  }

  const int site = blockIdx.x * 8 + w * 2 + s2;
  const int b = site / YX_;
  const int yx = site % YX_;
  const int y = yx / X_, x = yx % X_;
  const int yc = clampi(y, 2, 189), xc = clampi(x, 2, 189);
  const u32 sbase = (u32)(((b * Y_ + (yc - 2)) * X_ + (xc - 2)) * 256 + h * 32);
  const char* Kc = (const char*)Kb;
  const char* Vc = (const char*)Vb;

  // Q packed (prescaled by QSCALE, + temp & query-spatial emb)
  u32 qp[3][8];
  #pragma unroll
  for (int q = 0; q < 3; ++q){
    const u16* qptr = Qb + ((size_t)((q * B_ + b) * Y_ + y) * X_ + x) * 128 + h * 16;
    const uint4 a = *(const uint4*)qptr;
    const uint4 c = *(const uint4*)(qptr + 8);
    qp[q][0] = a.x; qp[q][1] = a.y; qp[q][2] = a.z; qp[q][3] = a.w;
    qp[q][4] = c.x; qp[q][5] = c.y; qp[q][6] = c.z; qp[q][7] = c.w;
  }

  // qse[q][so][h] = Qs . spatial_emb[so] (per head), so striped over the 4 slots
  float* qsl = &qse[w][s2][0];
  #pragma unroll
  for (int sj = 0; sj < 7; ++sj){
    const int so = sj * 4 + slot;
    if (so < 25){
      const u16* sp = se_bf + so * 128 + h * 16;
      const uint4 e0 = *(const uint4*)sp;
      const uint4 e1 = *(const uint4*)(sp + 8);
      u32 ep[8] = {e0.x, e0.y, e0.z, e0.w, e1.x, e1.y, e1.z, e1.w};
      #pragma unroll
      for (int q = 0; q < 3; ++q){
        float d = 0.f;
        #pragma unroll
        for (int i = 0; i < 8; ++i) d = dot2bf(qp[q][i], ep[i], d);
        qsl[q * 200 + so * 8 + h] = d;
      }
    }
  }
  __syncthreads();

  float ll[3] = {0.f, 0.f, 0.f};
  f32x2 acc[3][8];
  #pragma unroll
  for (int q = 0; q < 3; ++q)
    #pragma unroll
    for (int i = 0; i < 8; ++i) acc[q][i] = (f32x2){0.f, 0.f};

  #pragma unroll
  for (int j = 0; j < 19; ++j){
    const int kk = j * 4 + slot;
    const u32 e = tbl[kk];
    const u32 boff = sbase + (e & 0xffffff00u);
    const int s8 = (int)(e & 0xffu);
    const uint4 k0 = *(const uint4*)(Kc + boff);
    const uint4 k1 = *(const uint4*)(Kc + boff + 16);
    const uint4 v0 = *(const uint4*)(Vc + boff);
    const uint4 v1 = *(const uint4*)(Vc + boff + 16);
    const u32 kp[8] = {k0.x, k0.y, k0.z, k0.w, k1.x, k1.y, k1.z, k1.w};
    f32x2 vf[8];
    vf[0] = bfp(v0.x); vf[1] = bfp(v0.y); vf[2] = bfp(v0.z); vf[3] = bfp(v0.w);
    vf[4] = bfp(v1.x); vf[5] = bfp(v1.y); vf[6] = bfp(v1.z); vf[7] = bfp(v1.w);

    #pragma unroll
    for (int q = 0; q < 3; ++q){
      float d = qsl[q * 200 + s8 + h];
      #pragma unroll
      for (int i = 0; i < 8; ++i) d = dot2bf(qp[q][i], kp[i], d);
      float p = fexp2(d);
      if (j == 18 && slot >= 3) p = 0.f;    // only keys 72..74 are real in the tail
      ll[q] += p;
      const f32x2 pp = {p, p};
      #pragma unroll
      for (int i = 0; i < 8; ++i) acc[q][i] += pp * vf[i];
    }
  }

  // merge across the 4 key-slot groups (lanes xor 8/16 share the same site & head)
  #pragma unroll
  for (int q = 0; q < 3; ++q){
    ll[q] += __shfl_xor(ll[q], 8);
    ll[q] += __shfl_xor(ll[q], 16);
    #pragma unroll
    for (int i = 0; i < 8; ++i){
      acc[q][i] += shfl2(acc[q][i], 8);
      acc[q][i] += shfl2(acc[q][i], 16);
    }
  }

  // slot q (<3) stores query-frame q's output over its site's Q row
  #pragma unroll
  for (int q = 0; q < 3; ++q){
    if (slot == q){
      const float inv = 1.0f / ll[q];
      uint4 o0, o1;
      {
        const f32x2 t0 = acc[q][0] * inv, t1 = acc[q][1] * inv;
        const f32x2 t2 = acc[q][2] * inv, t3 = acc[q][3] * inv;
        o0.x = (u32)f2bf(t0.x) | ((u32)f2bf(t0.y) << 16);
        o0.y = (u32)f2bf(t1.x) | ((u32)f2bf(t1.y) << 16);
        o0.z = (u32)f2bf(t2.x) | ((u32)f2bf(t2.y) << 16);
        o0.w = (u32)f2bf(t3.x) | ((u32)f2bf(t3.y) << 16);
      }
      {
        const f32x2 t0 = acc[q][4] * inv, t1 = acc[q][5] * inv;
        const f32x2 t2 = acc[q][6] * inv, t3 = acc[q][7] * inv;
        o1.x = (u32)f2bf(t0.x) | ((u32)f2bf(t0.y) << 16);
        o1.y = (u32)f2bf(t1.x) | ((u32)f2bf(t1.y) << 16);
        o1.z = (u32)f2bf(t2.x) | ((u32)f2bf(t2.y) << 16);
        o1.w = (u32)f2bf(t3.x) | ((u32)f2bf(t3.y) << 16);
      }
      u16* dst = Qb + ((size_t)((q * B_ + b) * Y_ + y) * X_ + x) * 128 + h * 16;
      *(uint4*)dst = o0;
      *(uint4*)(dst + 8) = o1;
    }
  }
}

// ---------------- kernel 3: output projection (attnout x Wout) ----------------
__global__ __launch_bounds__(256) void out_kernel(
    const u16* __restrict__ Ab, const u16* __restrict__ WT3, float* __restrict__ out){
  const int tid = threadIdx.x;
  const int w = tid >> 6, l = tid & 63;
  const int l16 = l & 15, lg = l >> 4;
  const int m0 = blockIdx.x * 128;

  f32x4 acc[2][8];
  #pragma unroll
  for (int mr = 0; mr < 2; ++mr)
    #pragma unroll
    for (int nf = 0; nf < 8; ++nf)
      acc[mr][nf] = (f32x4){0.f, 0.f, 0.f, 0.f};

  #pragma unroll
  for (int ks = 0; ks < 4; ++ks){
    short8 af[2];
    #pragma unroll
    for (int mr = 0; mr < 2; ++mr)
      af[mr] = *(const short8*)(Ab + (size_t)(m0 + w * 32 + mr * 16 + l16) * 128 + ks * 32 + lg * 8);
    #pragma unroll
    for (int nf = 0; nf < 8; ++nf){
      const short8 bf = *(const short8*)(WT3 + (nf * 16 + l16) * 128 + ks * 32 + lg * 8);
      acc[0][nf] = __builtin_amdgcn_mfma_f32_16x16x32_bf16(af[0], bf, acc[0][nf], 0, 0, 0);
      acc[1][nf] = __builtin_amdgcn_mfma_f32_16x16x32_bf16(af[1], bf, acc[1][nf], 0, 0, 0);
    }
  }

  #pragma unroll
  for (int mr = 0; mr < 2; ++mr)
    #pragma unroll
    for (int nf = 0; nf < 8; ++nf)
      #pragma unroll
      for (int i = 0; i < 4; ++i)
        out[(size_t)(m0 + w * 32 + mr * 16 + lg * 4 + i) * 128 + nf * 16 + l16] = acc[mr][nf][i];
}

extern "C" void kernel_launch(void* const* d_in, const int* in_sizes, int n_in,
                              void* d_out, int out_size, void* d_ws, size_t ws_size,
                              hipStream_t stream){
  const float* frames      = (const float*)d_in[0];
  const float* Wq          = (const float*)d_in[1];
  const float* Wk          = (const float*)d_in[2];
  const float* Wv          = (const float*)d_in[3];
  const float* Wo          = (const float*)d_in[4];
  const float* temp_emb    = (const float*)d_in[5];
  const float* spatial_emb = (const float*)d_in[6];

  u16* WT    = (u16*)d_ws;                      // [4][128][128] bf16 (n-major)
  u16* se_bf = WT + 4 * 16384;                  // [25][128] bf16
  u16* Qb    = WT + 68736;                      // [N_][128] bf16 (Q, then attnout)
  u16* Kb    = (u16*)d_out;                     // [N_][128] bf16 — reuse output buffer
  u16* Vb    = Kb + (size_t)N_ * 128;           // [N_][128] bf16 — exactly fills d_out
  float* out = (float*)d_out;

  wt_kernel<<<269, 256, 0, stream>>>(Wq, Wk, Wv, Wo, spatial_emb, WT, se_bf);
  qkv_kernel<<<dim3(N_ / 128, 3), 256, 0, stream>>>(frames, WT, Qb, Kb, Vb, temp_emb, spatial_emb);
  attn_kernel<<<NS_ / 8, 256, 0, stream>>>(Kb, Vb, Qb, se_bf);
  out_kernel<<<N_ / 128, 256, 0, stream>>>(Qb, WT + 3 * 16384, out);
}

// Round 9
// 343.214 us; speedup vs baseline: 1.6945x; 1.1787x over previous
//
#include <hip/hip_runtime.h>
#include <cstdint>
#include <cstddef>

#define T_ 3
#define B_ 2
#define Y_ 192
#define X_ 192
#define YX_ 36864          // Y_*X_
#define N_ 221184          // T_*B_*Y_*X_
#define NS_ 73728          // B_*Y_*X_

typedef __attribute__((ext_vector_type(8))) short short8;
typedef __attribute__((ext_vector_type(4))) float f32x4;
typedef __attribute__((ext_vector_type(2))) float f32x2;
typedef unsigned short u16;
typedef unsigned int u32;

__device__ __forceinline__ u16 f2bf(float f){
  u32 x = __builtin_bit_cast(u32, f);
  x += 0x7fffu + ((x >> 16) & 1u);          // RNE
  return (u16)(x >> 16);
}
__device__ __forceinline__ float bflo(u32 u){ return __builtin_bit_cast(float, u << 16); }
__device__ __forceinline__ float bfhi(u32 u){ return __builtin_bit_cast(float, u & 0xffff0000u); }
__device__ __forceinline__ f32x2 bfp(u32 u){
  f32x2 r; r.x = bflo(u); r.y = bfhi(u); return r;
}
__device__ __forceinline__ int clampi(int v, int lo, int hi){ return v < lo ? lo : (v > hi ? hi : v); }
__device__ __forceinline__ f32x2 shfl2(f32x2 v, int m){
  f32x2 r; r.x = __shfl_xor(v.x, m); r.y = __shfl_xor(v.y, m); return r;
}

#if __has_builtin(__builtin_amdgcn_fdot2_f32_bf16)
typedef __attribute__((ext_vector_type(2))) __bf16 bf16x2;
__device__ __forceinline__ float dot2bf(u32 a, u32 b, float c){
  return __builtin_amdgcn_fdot2_f32_bf16(__builtin_bit_cast(bf16x2, a),
                                         __builtin_bit_cast(bf16x2, b), c, false);
}
#else
__device__ __forceinline__ float dot2bf(u32 a, u32 b, float c){
  return fmaf(bfhi(a), bfhi(b), fmaf(bflo(a), bflo(b), c));
}
#endif

#if __has_builtin(__builtin_amdgcn_exp2f)
__device__ __forceinline__ float fexp2(float x){ return __builtin_amdgcn_exp2f(x); }
#else
__device__ __forceinline__ float fexp2(float x){ return exp2f(x); }
#endif

// Q prescale: 1/sqrt(F) * log2(e), so score exp() becomes exp2() with no extra mul
#define QSCALE 0.36067376022224085f

// ---------------- kernel 0: weights -> bf16 n-major; spatial_emb -> bf16 ----------------
__global__ __launch_bounds__(256) void wt_kernel(
    const float* __restrict__ Wq, const float* __restrict__ Wk,
    const float* __restrict__ Wv, const float* __restrict__ Wo,
    const float* __restrict__ spatial_emb, u16* __restrict__ WT, u16* __restrict__ se_bf){
  int idx = blockIdx.x * 256 + threadIdx.x;
  if (idx < 65536){
    int g = idx >> 14;
    int r = (idx >> 7) & 127;                   // k
    int c = idx & 127;                          // n
    const float* W = (g == 0) ? Wq : (g == 1) ? Wk : (g == 2) ? Wv : Wo;
    WT[g * 16384 + c * 128 + r] = f2bf(W[r * 128 + c]);
  } else if (idx < 65536 + 3200){
    se_bf[idx - 65536] = f2bf(spatial_emb[idx - 65536]);
  }
}

// ---------------- kernel 1: fused QKV projection, persistent A-frags ----------------
// One block = 128 rows. A-tile loaded ONCE into bf16 register fragments, then
// g-loop {Q,K,V}: 64 MFMA + LDS-bounce epilogue (+emb). frames read 1x total.
__global__ __launch_bounds__(256, 2) void qkv_kernel(
    const float* __restrict__ frames, const u16* __restrict__ WT,
    u16* __restrict__ Qb, u16* __restrict__ Kb, u16* __restrict__ Vb,
    const float* __restrict__ temp_emb, const float* __restrict__ spatial_emb){
  __shared__ float tile[128 * 128];
  const int tid = threadIdx.x;
  const int w = tid >> 6, l = tid & 63;
  const int l16 = l & 15, lg = l >> 4;
  const int m0 = blockIdx.x * 128;

  // ---- load A fragments once (bf16), reused by all 3 GEMMs ----
  short8 af[4][2];
  #pragma unroll
  for (int ks = 0; ks < 4; ++ks)
    #pragma unroll
    for (int mr = 0; mr < 2; ++mr){
      const float* ap = frames + (size_t)(m0 + w * 32 + mr * 16 + l16) * 128 + ks * 32 + lg * 8;
      const f32x4 a0 = *(const f32x4*)ap;
      const f32x4 a1 = *(const f32x4*)(ap + 4);
      short8 t;
      t[0] = (short)f2bf(a0[0]); t[1] = (short)f2bf(a0[1]);
      t[2] = (short)f2bf(a0[2]); t[3] = (short)f2bf(a0[3]);
      t[4] = (short)f2bf(a1[0]); t[5] = (short)f2bf(a1[1]);
      t[6] = (short)f2bf(a1[2]); t[7] = (short)f2bf(a1[3]);
      af[ks][mr] = t;
    }

  #pragma unroll
  for (int g = 0; g < 3; ++g){
    const u16* wt = WT + g * 16384;
    f32x4 acc[2][8];
    #pragma unroll
    for (int mr = 0; mr < 2; ++mr)
      #pragma unroll
      for (int nf = 0; nf < 8; ++nf)
        acc[mr][nf] = (f32x4){0.f, 0.f, 0.f, 0.f};

    #pragma unroll
    for (int ks = 0; ks < 4; ++ks)
      #pragma unroll
      for (int nf = 0; nf < 8; ++nf){
        const short8 bf = *(const short8*)(wt + (nf * 16 + l16) * 128 + ks * 32 + lg * 8);
        acc[0][nf] = __builtin_amdgcn_mfma_f32_16x16x32_bf16(af[ks][0], bf, acc[0][nf], 0, 0, 0);
        acc[1][nf] = __builtin_amdgcn_mfma_f32_16x16x32_bf16(af[ks][1], bf, acc[1][nf], 0, 0, 0);
      }

    if (g > 0) __syncthreads();                 // previous epilogue reads done
    #pragma unroll
    for (int mr = 0; mr < 2; ++mr)
      #pragma unroll
      for (int nf = 0; nf < 8; ++nf)
        #pragma unroll
        for (int i = 0; i < 4; ++i)
          tile[(w * 32 + mr * 16 + lg * 4 + i) * 128 + nf * 16 + l16] = acc[mr][nf][i];
    __syncthreads();

    u16* outp = (g == 0) ? Qb : (g == 1) ? Kb : Vb;
    #pragma unroll
    for (int it = 0; it < 16; ++it){
      const int idx = it * 256 + tid;
      const int r = idx >> 5;
      const int c4 = (idx & 31) * 4;
      f32x4 v = *(const f32x4*)&tile[r * 128 + c4];
      const int p = m0 + r;
      const int t = p / (B_ * YX_);
      if (g <= 1){                          // temporal emb for Q and K
        const float* te = temp_emb + t * 128 + c4;
        v[0] += te[0]; v[1] += te[1]; v[2] += te[2]; v[3] += te[3];
      }
      if (g == 0){                          // query spatial emb + QSCALE prescale
        const int yx = p % YX_;
        const int y = yx / X_, x = yx % X_;
        const int yrel = y - clampi(y, 2, Y_ - 3) + 2;
        const int xrel = x - clampi(x, 2, X_ - 3) + 2;
        const float* se = spatial_emb + (yrel * 5 + xrel) * 128 + c4;
        v[0] = (v[0] + se[0]) * QSCALE; v[1] = (v[1] + se[1]) * QSCALE;
        v[2] = (v[2] + se[2]) * QSCALE; v[3] = (v[3] + se[3]) * QSCALE;
      }
      uint2 pk;
      pk.x = (u32)f2bf(v[0]) | ((u32)f2bf(v[1]) << 16);
      pk.y = (u32)f2bf(v[2]) | ((u32)f2bf(v[3]) << 16);
      *(uint2*)(outp + (size_t)p * 128 + c4) = pk;
    }
  }
}

// ---------------- kernel 2: scalar attention, 2 sites x 4 key-slots x 8 heads per wave ----------
// lane (s2=l>>5, slot=(l>>3)&3, h=l&7): site s2, head h (16ch), keys slot, slot+4, ...
// amdgpu_waves_per_eu(4,4): pin allocator at the 128-VGPR band -> no spill (R8 spilled at 64).
__global__ __attribute__((amdgpu_waves_per_eu(4, 4))) __launch_bounds__(256) void attn_kernel(
    const u16* __restrict__ Kb, const u16* __restrict__ Vb,
    u16* __restrict__ Qb, const u16* __restrict__ se_bf){
  __shared__ float qse[4][2][600];          // [wave][site2][q*200 + s*8 + h]
  __shared__ u32 tbl[80];                   // byte offset (x256) | s*8 in low byte
  const int tid = threadIdx.x;
  const int w = tid >> 6, l = tid & 63;
  const int s2 = l >> 5, slot = (l >> 3) & 3, h = l & 7;

  if (tid < 80){                            // offset table (padded: 75..79 -> key 74)
    const int kk = tid > 74 ? 74 : tid;
    const int t = kk / 25, s = kk - t * 25;
    const int dy = s / 5, dx = s - dy * 5;
    tbl[tid] = (u32)((((t * (B_ * Y_) + dy) * X_ + dx) * 256) | (s * 8));
  }

  const int site = blockIdx.x * 8 + w * 2 + s2;
  const int b = site / YX_;
  const int yx = site % YX_;
  const int y = yx / X_, x = yx % X_;
  const int yc = clampi(y, 2, 189), xc = clampi(x, 2, 189);
  const u32 sbase = (u32)(((b * Y_ + (yc - 2)) * X_ + (xc - 2)) * 256 + h * 32);
  const char* Kc = (const char*)Kb;
  const char* Vc = (const char*)Vb;

  // Q packed (prescaled by QSCALE, + temp & query-spatial emb)
  u32 qp[3][8];
  #pragma unroll
  for (int q = 0; q < 3; ++q){
    const u16* qptr = Qb + ((size_t)((q * B_ + b) * Y_ + y) * X_ + x) * 128 + h * 16;
    const uint4 a = *(const uint4*)qptr;
    const uint4 c = *(const uint4*)(qptr + 8);
    qp[q][0] = a.x; qp[q][1] = a.y; qp[q][2] = a.z; qp[q][3] = a.w;
    qp[q][4] = c.x; qp[q][5] = c.y; qp[q][6] = c.z; qp[q][7] = c.w;
  }

  // qse[q][so][h] = Qs . spatial_emb[so] (per head), so striped over the 4 slots
  float* qsl = &qse[w][s2][0];
  #pragma unroll
  for (int sj = 0; sj < 7; ++sj){
    const int so = sj * 4 + slot;
    if (so < 25){
      const u16* sp = se_bf + so * 128 + h * 16;
      const uint4 e0 = *(const uint4*)sp;
      const uint4 e1 = *(const uint4*)(sp + 8);
      u32 ep[8] = {e0.x, e0.y, e0.z, e0.w, e1.x, e1.y, e1.z, e1.w};
      #pragma unroll
      for (int q = 0; q < 3; ++q){
        float d = 0.f;
        #pragma unroll
        for (int i = 0; i < 8; ++i) d = dot2bf(qp[q][i], ep[i], d);
        qsl[q * 200 + so * 8 + h] = d;
      }
    }
  }
  __syncthreads();

  float ll[3] = {0.f, 0.f, 0.f};
  f32x2 acc[3][8];
  #pragma unroll
  for (int q = 0; q < 3; ++q)
    #pragma unroll
    for (int i = 0; i < 8; ++i) acc[q][i] = (f32x2){0.f, 0.f};

  #pragma unroll
  for (int j = 0; j < 19; ++j){
    const int kk = j * 4 + slot;
    const u32 e = tbl[kk];
    const u32 boff = sbase + (e & 0xffffff00u);
    const int s8 = (int)(e & 0xffu);
    const uint4 k0 = *(const uint4*)(Kc + boff);
    const uint4 k1 = *(const uint4*)(Kc + boff + 16);
    const uint4 v0 = *(const uint4*)(Vc + boff);
    const uint4 v1 = *(const uint4*)(Vc + boff + 16);
    const u32 kp[8] = {k0.x, k0.y, k0.z, k0.w, k1.x, k1.y, k1.z, k1.w};
    f32x2 vf[8];
    vf[0] = bfp(v0.x); vf[1] = bfp(v0.y); vf[2] = bfp(v0.z); vf[3] = bfp(v0.w);
    vf[4] = bfp(v1.x); vf[5] = bfp(v1.y); vf[6] = bfp(v1.z); vf[7] = bfp(v1.w);

    #pragma unroll
    for (int q = 0; q < 3; ++q){
      float d = qsl[q * 200 + s8 + h];
      #pragma unroll
      for (int i = 0; i < 8; ++i) d = dot2bf(qp[q][i], kp[i], d);
      float p = fexp2(d);
      if (j == 18 && slot >= 3) p = 0.f;    // only keys 72..74 are real in the tail
      ll[q] += p;
      const f32x2 pp = {p, p};
      #pragma unroll
      for (int i = 0; i < 8; ++i) acc[q][i] += pp * vf[i];
    }
  }

  // merge across the 4 key-slot groups (lanes xor 8/16 share the same site & head)
  #pragma unroll
  for (int q = 0; q < 3; ++q){
    ll[q] += __shfl_xor(ll[q], 8);
    ll[q] += __shfl_xor(ll[q], 16);
    #pragma unroll
    for (int i = 0; i < 8; ++i){
      acc[q][i] += shfl2(acc[q][i], 8);
      acc[q][i] += shfl2(acc[q][i], 16);
    }
  }

  // slot q (<3) stores query-frame q's output over its site's Q row
  #pragma unroll
  for (int q = 0; q < 3; ++q){
    if (slot == q){
      const float inv = 1.0f / ll[q];
      uint4 o0, o1;
      {
        const f32x2 t0 = acc[q][0] * inv, t1 = acc[q][1] * inv;
        const f32x2 t2 = acc[q][2] * inv, t3 = acc[q][3] * inv;
        o0.x = (u32)f2bf(t0.x) | ((u32)f2bf(t0.y) << 16);
        o0.y = (u32)f2bf(t1.x) | ((u32)f2bf(t1.y) << 16);
        o0.z = (u32)f2bf(t2.x) | ((u32)f2bf(t2.y) << 16);
        o0.w = (u32)f2bf(t3.x) | ((u32)f2bf(t3.y) << 16);
      }
      {
        const f32x2 t0 = acc[q][4] * inv, t1 = acc[q][5] * inv;
        const f32x2 t2 = acc[q][6] * inv, t3 = acc[q][7] * inv;
        o1.x = (u32)f2bf(t0.x) | ((u32)f2bf(t0.y) << 16);
        o1.y = (u32)f2bf(t1.x) | ((u32)f2bf(t1.y) << 16);
        o1.z = (u32)f2bf(t2.x) | ((u32)f2bf(t2.y) << 16);
        o1.w = (u32)f2bf(t3.x) | ((u32)f2bf(t3.y) << 16);
      }
      u16* dst = Qb + ((size_t)((q * B_ + b) * Y_ + y) * X_ + x) * 128 + h * 16;
      *(uint4*)dst = o0;
      *(uint4*)(dst + 8) = o1;
    }
  }
}

// ---------------- kernel 3: output projection (attnout x Wout) ----------------
__global__ __launch_bounds__(256) void out_kernel(
    const u16* __restrict__ Ab, const u16* __restrict__ WT3, float* __restrict__ out){
  const int tid = threadIdx.x;
  const int w = tid >> 6, l = tid & 63;
  const int l16 = l & 15, lg = l >> 4;
  const int m0 = blockIdx.x * 128;

  f32x4 acc[2][8];
  #pragma unroll
  for (int mr = 0; mr < 2; ++mr)
    #pragma unroll
    for (int nf = 0; nf < 8; ++nf)
      acc[mr][nf] = (f32x4){0.f, 0.f, 0.f, 0.f};

  #pragma unroll
  for (int ks = 0; ks < 4; ++ks){
    short8 af[2];
    #pragma unroll
    for (int mr = 0; mr < 2; ++mr)
      af[mr] = *(const short8*)(Ab + (size_t)(m0 + w * 32 + mr * 16 + l16) * 128 + ks * 32 + lg * 8);
    #pragma unroll
    for (int nf = 0; nf < 8; ++nf){
      const short8 bf = *(const short8*)(WT3 + (nf * 16 + l16) * 128 + ks * 32 + lg * 8);
      acc[0][nf] = __builtin_amdgcn_mfma_f32_16x16x32_bf16(af[0], bf, acc[0][nf], 0, 0, 0);
      acc[1][nf] = __builtin_amdgcn_mfma_f32_16x16x32_bf16(af[1], bf, acc[1][nf], 0, 0, 0);
    }
  }

  #pragma unroll
  for (int mr = 0; mr < 2; ++mr)
    #pragma unroll
    for (int nf = 0; nf < 8; ++nf)
      #pragma unroll
      for (int i = 0; i < 4; ++i)
        out[(size_t)(m0 + w * 32 + mr * 16 + lg * 4 + i) * 128 + nf * 16 + l16] = acc[mr][nf][i];
}

extern "C" void kernel_launch(void* const* d_in, const int* in_sizes, int n_in,
                              void* d_out, int out_size, void* d_ws, size_t ws_size,
                              hipStream_t stream){
  const float* frames      = (const float*)d_in[0];
  const float* Wq          = (const float*)d_in[1];
  const float* Wk          = (const float*)d_in[2];
  const float* Wv          = (const float*)d_in[3];
  const float* Wo          = (const float*)d_in[4];
  const float* temp_emb    = (const float*)d_in[5];
  const float* spatial_emb = (const float*)d_in[6];

  u16* WT    = (u16*)d_ws;                      // [4][128][128] bf16 (n-major)
  u16* se_bf = WT + 4 * 16384;                  // [25][128] bf16
  u16* Qb    = WT + 68736;                      // [N_][128] bf16 (Q, then attnout)
  u16* Kb    = (u16*)d_out;                     // [N_][128] bf16 — reuse output buffer
  u16* Vb    = Kb + (size_t)N_ * 128;           // [N_][128] bf16 — exactly fills d_out
  float* out = (float*)d_out;

  wt_kernel<<<269, 256, 0, stream>>>(Wq, Wk, Wv, Wo, spatial_emb, WT, se_bf);
  qkv_kernel<<<N_ / 128, 256, 0, stream>>>(frames, WT, Qb, Kb, Vb, temp_emb, spatial_emb);
  attn_kernel<<<NS_ / 8, 256, 0, stream>>>(Kb, Vb, Qb, se_bf);
  out_kernel<<<N_ / 128, 256, 0, stream>>>(Qb, WT + 3 * 16384, out);
}